// Round 3
// baseline (844.156 us; speedup 1.0000x reference)
//
#include <hip/hip_runtime.h>
#include <hip/hip_bf16.h>
#include <math.h>

// Problem constants
constexpr int B_   = 512;
constexpr int S_   = 200;
constexpr int D_   = 512;
constexpr int NH_  = 8;
constexpr int DK_  = 64;
constexpr int LBLK = 4;     // 2*K
constexpr int NITER = 3;
constexpr int TD_  = 1536;  // 3*D
#define NEGV (-1000000000.0f)

using bf16 = __hip_bfloat16;
typedef __attribute__((ext_vector_type(8))) short bf16x8;
typedef __attribute__((ext_vector_type(4))) float f32x4;

__device__ __forceinline__ float wred(float x) {
#pragma unroll
    for (int o = 32; o; o >>= 1) x += __shfl_xor(x, o);
    return x;
}

// ---------------- prep: f32 -> bf16 conversions ----------------
__global__ void __launch_bounds__(256) k_cvt(const float* __restrict__ src,
                                             bf16* __restrict__ dst, int n) {
    int i = blockIdx.x * 256 + threadIdx.x;
    if (i < n) dst[i] = __float2bfloat16(src[i]);
}

// transpose (TD_ x D_) -> (D_ x TD_) with bf16 convert:  dst[k*TD_+n] = src[n*D_+k]
__global__ void __launch_bounds__(256) k_tcvt(const float* __restrict__ src,
                                              bf16* __restrict__ dst) {
    int i = blockIdx.x * 256 + threadIdx.x;
    if (i >= D_ * TD_) return;
    int k = i / TD_, n = i - k * TD_;
    dst[i] = __float2bfloat16(src[n * D_ + k]);
}

// ---------------- stage 1: h_blk + a = tanh(h_blk@W1)@W2 ----------------
__global__ void __launch_bounds__(256) k_blockscore(
        const float* __restrict__ emb, const float* __restrict__ W1,
        const float* __restrict__ W2, const int* __restrict__ stc,
        const int* __restrict__ offs, const int* __restrict__ sep,
        float* __restrict__ hblk, float* __restrict__ a_out,
        int* __restrict__ se_out) {
    int b = blockIdx.x;
    int t = threadIdx.x;
    int off = offs[b], slen = stc[b];
    int sA = sep[b * 2 + 0], sB = sep[b * 2 + 1];
    int idx = (sA < off ? 1 : 0) + (sB < off ? 1 : 0);
    int prev = (idx == 2) ? sB : sA;          // sep[clip(idx-1,0,1)]
    int nxt  = (idx == 0) ? sA : sB;          // sep[clip(idx,0,1)]
    int left = (idx > 0) ? prev + 1 : 0;
    int right = (idx < 2) ? nxt : slen;
    int start = max(off - 2, left);
    int end   = min(off + 2, right);

    __shared__ float hs[LBLK][D_];
    {
        int l = t >> 6, lane = t & 63;
        int ind = start + l;
        bool valid = ind < end;
        float v0x=0,v0y=0,v0z=0,v0w=0,v1x=0,v1y=0,v1z=0,v1w=0;
        if (valid) {
            int ic = min(max(ind, 0), S_ - 1);
            const float* src = emb + ((size_t)b * S_ + ic) * D_ + lane * 8;
            float4 u0 = *(const float4*)src;
            float4 u1 = *(const float4*)(src + 4);
            v0x=u0.x; v0y=u0.y; v0z=u0.z; v0w=u0.w;
            v1x=u1.x; v1y=u1.y; v1z=u1.z; v1w=u1.w;
        }
        int base = lane * 8;
        hs[l][base+0]=v0x; hs[l][base+1]=v0y; hs[l][base+2]=v0z; hs[l][base+3]=v0w;
        hs[l][base+4]=v1x; hs[l][base+5]=v1y; hs[l][base+6]=v1z; hs[l][base+7]=v1w;
        float* g = hblk + ((size_t)b * LBLK + l) * D_ + base;
        g[0]=v0x; g[1]=v0y; g[2]=v0z; g[3]=v0w; g[4]=v1x; g[5]=v1y; g[6]=v1z; g[7]=v1w;
    }
    __syncthreads();

    float pa0 = 0.f, pa1 = 0.f, pa2 = 0.f, pa3 = 0.f;
#pragma unroll
    for (int cc = 0; cc < 2; ++cc) {
        int col = t + cc * 256;
        float a0 = 0.f, a1 = 0.f, a2 = 0.f, a3 = 0.f;
        for (int d = 0; d < D_; ++d) {
            float w = W1[(size_t)d * 512 + col];
            a0 += hs[0][d] * w; a1 += hs[1][d] * w;
            a2 += hs[2][d] * w; a3 += hs[3][d] * w;
        }
        float w2 = W2[col];
        pa0 += tanhf(a0) * w2; pa1 += tanhf(a1) * w2;
        pa2 += tanhf(a2) * w2; pa3 += tanhf(a3) * w2;
    }
    __shared__ float red[256];
    float pv[4] = {pa0, pa1, pa2, pa3};
#pragma unroll
    for (int l = 0; l < 4; ++l) {
        red[t] = pv[l]; __syncthreads();
        for (int st = 128; st; st >>= 1) {
            if (t < st) red[t] += red[t + st];
            __syncthreads();
        }
        if (t == 0) a_out[b * 4 + l] = red[0];
        __syncthreads();
    }
    if (t == 0) { se_out[b * 2] = start; se_out[b * 2 + 1] = end; }
}

// ---------------- stage 2: cross-batch softmax + masked row softmax ----------------
__global__ void __launch_bounds__(512) k_score(const float* __restrict__ a_in,
                                               const int* __restrict__ se,
                                               float* __restrict__ score) {
    int b = threadIdx.x;  // 512 threads, 1 block
    float av[4], s1[4];
#pragma unroll
    for (int l = 0; l < 4; ++l) av[l] = a_in[b * 4 + l];
    __shared__ float red[512];
#pragma unroll
    for (int l = 0; l < 4; ++l) {
        red[b] = av[l]; __syncthreads();
        for (int st = 256; st; st >>= 1) {
            if (b < st) red[b] = fmaxf(red[b], red[b + st]);
            __syncthreads();
        }
        float mx = red[0]; __syncthreads();
        float e = expf(av[l] - mx);
        red[b] = e; __syncthreads();
        for (int st = 256; st; st >>= 1) {
            if (b < st) red[b] += red[b + st];
            __syncthreads();
        }
        s1[l] = e / red[0];
        __syncthreads();
    }
    int start = se[b * 2], end = se[b * 2 + 1];
    float x[4], mx2 = -1e30f;
#pragma unroll
    for (int l = 0; l < 4; ++l) {
        x[l] = (start + l < end) ? s1[l] : NEGV;
        mx2 = fmaxf(mx2, x[l]);
    }
    float s = 0.f, e4[4];
#pragma unroll
    for (int l = 0; l < 4; ++l) { e4[l] = expf(x[l] - mx2); s += e4[l]; }
    float inv = 1.f / s;
#pragma unroll
    for (int l = 0; l < 4; ++l) score[b * 4 + l] = e4[l] * inv;
}

// ---------------- stage 3: b0 = score . h_blk, + pe[0], LN -> b_t ----------------
__global__ void __launch_bounds__(64) k_b0(
        const float* __restrict__ hblk, const float* __restrict__ score,
        const float* __restrict__ pe, const float* __restrict__ g,
        const float* __restrict__ bb, float* __restrict__ bt,
        bf16* __restrict__ btb) {
    int b = blockIdx.x, lane = threadIdx.x;
    float sc0 = score[b*4+0], sc1 = score[b*4+1], sc2 = score[b*4+2], sc3 = score[b*4+3];
    const float* hb = hblk + (size_t)b * LBLK * D_ + lane * 8;
    float v[8];
#pragma unroll
    for (int j = 0; j < 8; ++j) {
        float x = pe[lane * 8 + j];
        x += sc0 * hb[j] + sc1 * hb[D_ + j] + sc2 * hb[2*D_ + j] + sc3 * hb[3*D_ + j];
        v[j] = x;
    }
    float sum = 0.f;
#pragma unroll
    for (int j = 0; j < 8; ++j) sum += v[j];
    sum = wred(sum);
    float mean = sum * (1.f / 512.f);
    float sq = 0.f;
#pragma unroll
    for (int j = 0; j < 8; ++j) { float c = v[j] - mean; sq += c * c; }
    sq = wred(sq);
    float rstd = rsqrtf(sq * (1.f / 512.f) + 1e-5f);
#pragma unroll
    for (int j = 0; j < 8; ++j) {
        int d = lane * 8 + j;
        float y = (v[j] - mean) * rstd * g[d] + bb[d];
        bt[(size_t)b * D_ + d] = y;
        btb[(size_t)b * D_ + d] = __float2bfloat16(y);
    }
}

// ---------------- stage 4: H = LN(emb + pe[ip] + seg_emb[seg]) -> bf16 ----------------
__global__ void __launch_bounds__(256) k_H(
        const float* __restrict__ emb, const float* __restrict__ pe,
        const float* __restrict__ seg_emb, const float* __restrict__ g,
        const float* __restrict__ bb, const int* __restrict__ stc,
        const int* __restrict__ offs, bf16* __restrict__ Hc,
        int b0, int nrows) {
    int rid = blockIdx.x * 4 + (threadIdx.x >> 6);
    if (rid >= nrows) return;
    int lane = threadIdx.x & 63;
    int bl = rid / S_;
    int s = rid - bl * S_;
    int b = b0 + bl;
    int slen = stc[b];
    if (s >= slen) return;
    int pos = offs[b];
    int ip = (s < pos) ? (pos - s) : (s + 1 - pos);
    if (ip > S_) ip = S_;
    int seg = (s >= pos) ? 1 : 0;
    const float* er = emb + ((size_t)b * S_ + s) * D_ + lane * 8;
    const float* pr = pe + (size_t)ip * D_ + lane * 8;
    const float* sr = seg_emb + seg * D_ + lane * 8;
    float4 e0 = *(const float4*)er, e1 = *(const float4*)(er + 4);
    float4 p0 = *(const float4*)pr, p1 = *(const float4*)(pr + 4);
    float4 q0 = *(const float4*)sr, q1 = *(const float4*)(sr + 4);
    float v[8];
    v[0]=e0.x+p0.x+q0.x; v[1]=e0.y+p0.y+q0.y; v[2]=e0.z+p0.z+q0.z; v[3]=e0.w+p0.w+q0.w;
    v[4]=e1.x+p1.x+q1.x; v[5]=e1.y+p1.y+q1.y; v[6]=e1.z+p1.z+q1.z; v[7]=e1.w+p1.w+q1.w;
    float sum = 0.f;
#pragma unroll
    for (int j = 0; j < 8; ++j) sum += v[j];
    sum = wred(sum);
    float mean = sum * (1.f / 512.f);
    float sq = 0.f;
#pragma unroll
    for (int j = 0; j < 8; ++j) { float c = v[j] - mean; sq += c * c; }
    sq = wred(sq);
    float rstd = rsqrtf(sq * (1.f / 512.f) + 1e-5f);
    union { uint4 u; bf16 h[8]; } o;
#pragma unroll
    for (int j = 0; j < 8; ++j) {
        int d = lane * 8 + j;
        o.h[j] = __float2bfloat16((v[j] - mean) * rstd * g[d] + bb[d]);
    }
    *(uint4*)(Hc + ((size_t)bl * S_ + s) * D_ + lane * 8) = o.u;
}

// ---------------- MFMA 64x64 GEMM tile (K=512, bf16 in, f32 acc) ----------------
__device__ __forceinline__ void gemm_tile64(
        const bf16* __restrict__ Abase, int lda,
        const bf16* __restrict__ Bbase, int ldb,
        const float* __restrict__ bias,
        float* __restrict__ Cf, bf16* __restrict__ Cb, int ldc,
        int rows_valid) {
    __shared__ bf16 As[64][40];
    __shared__ bf16 BsT[64][40];
    int t = threadIdx.x;
    int lane = t & 63, w = t >> 6;
    f32x4 acc0 = {0.f,0.f,0.f,0.f}, acc1 = {0.f,0.f,0.f,0.f};
    f32x4 acc2 = {0.f,0.f,0.f,0.f}, acc3 = {0.f,0.f,0.f,0.f};
    int arow = t >> 2, ac8 = (t & 3) * 8;   // A staging coords
    int bn = t & 63, bkb = (t >> 6) * 8;    // B staging coords

    for (int k0 = 0; k0 < 512; k0 += 32) {
        // stage A tile 64x32 (16B per thread)
        *(uint4*)&As[arow][ac8] =
            *(const uint4*)(Abase + (size_t)arow * lda + k0 + ac8);
        // stage B tile 32x64 transposed
        {
            union { uint4 u; bf16 h[8]; } tmp;
#pragma unroll
            for (int j = 0; j < 8; ++j)
                tmp.h[j] = Bbase[(size_t)(k0 + bkb + j) * ldb + bn];
            *(uint4*)&BsT[bn][bkb] = tmp.u;
        }
        __syncthreads();
        bf16x8 bfrag = *(const bf16x8*)&BsT[w * 16 + (lane & 15)][(lane >> 4) * 8];
        bf16x8 a0 = *(const bf16x8*)&As[ 0 + (lane & 15)][(lane >> 4) * 8];
        bf16x8 a1 = *(const bf16x8*)&As[16 + (lane & 15)][(lane >> 4) * 8];
        bf16x8 a2 = *(const bf16x8*)&As[32 + (lane & 15)][(lane >> 4) * 8];
        bf16x8 a3 = *(const bf16x8*)&As[48 + (lane & 15)][(lane >> 4) * 8];
        acc0 = __builtin_amdgcn_mfma_f32_16x16x32_bf16(a0, bfrag, acc0, 0, 0, 0);
        acc1 = __builtin_amdgcn_mfma_f32_16x16x32_bf16(a1, bfrag, acc1, 0, 0, 0);
        acc2 = __builtin_amdgcn_mfma_f32_16x16x32_bf16(a2, bfrag, acc2, 0, 0, 0);
        acc3 = __builtin_amdgcn_mfma_f32_16x16x32_bf16(a3, bfrag, acc3, 0, 0, 0);
        __syncthreads();
    }
    // C/D layout: col = lane&15, row = (lane>>4)*4 + r  (within each 16-row block)
    int col = w * 16 + (lane & 15);
    float bvv = bias[col];
    int rbase = (lane >> 4) * 4;
    f32x4 av[4] = {acc0, acc1, acc2, acc3};
#pragma unroll
    for (int rb = 0; rb < 4; ++rb) {
#pragma unroll
        for (int r = 0; r < 4; ++r) {
            int row = rb * 16 + rbase + r;
            if (row < rows_valid) {
                float vv = av[rb][r] + bvv;
                if (Cf) Cf[(size_t)row * ldc + col] = vv;
                if (Cb) Cb[(size_t)row * ldc + col] = __float2bfloat16(vv);
            }
        }
    }
}

__global__ void __launch_bounds__(256) k_gemm_kv(
        const bf16* __restrict__ Hc, const bf16* __restrict__ Wk,
        const bf16* __restrict__ Wv, const float* __restrict__ bk,
        const float* __restrict__ bv, bf16* __restrict__ kvk,
        bf16* __restrict__ kvv, const int* __restrict__ stc, int b0) {
    int nt = blockIdx.x;          // 0..15 : 0-7 -> K, 8-15 -> V
    int s0 = blockIdx.y * 64;     // 0,64,128,192
    int bl = blockIdx.z;
    int b = b0 + bl;
    int slen = stc[b];
    if (s0 >= slen) return;
    const bf16* A = Hc + ((size_t)bl * S_ + s0) * D_;
    const bf16* Bm; bf16* C; const float* bias; int n0;
    if (nt < 8) { Bm = Wk; C = kvk; bias = bk; n0 = nt * 64; }
    else        { Bm = Wv; C = kvv; bias = bv; n0 = (nt - 8) * 64; }
    int rows_valid = min(64, slen - s0);
    gemm_tile64(A, D_, Bm + n0, D_, bias + n0,
                nullptr, C + ((size_t)b * S_ + s0) * D_ + n0, D_, rows_valid);
}

__global__ void __launch_bounds__(256) k_gemm_flat(
        const bf16* __restrict__ A, int lda, const bf16* __restrict__ Bm, int ldb,
        const float* __restrict__ bias, float* __restrict__ Cf,
        bf16* __restrict__ Cb, int ldc) {
    int n0 = blockIdx.x * 64, m0 = blockIdx.y * 64;
    gemm_tile64(A + (size_t)m0 * lda, lda, Bm + n0, ldb, bias + n0,
                Cf ? Cf + (size_t)m0 * ldc + n0 : nullptr,
                Cb ? Cb + (size_t)m0 * ldc + n0 : nullptr, ldc, 64);
}

// ---------------- attention + LN(m_t) ----------------
__global__ void __launch_bounds__(256) k_attn(
        const float* __restrict__ q, const bf16* __restrict__ kk,
        const bf16* __restrict__ vv, const int* __restrict__ stc,
        const float* __restrict__ lng_g, const float* __restrict__ lng_b,
        float* __restrict__ mf, bf16* __restrict__ mb) {
    int b = blockIdx.x;
    int t = threadIdx.x, w = t >> 6, lane = t & 63;
    int slen = stc[b];
    const float* qp = q + (size_t)b * D_ + lane * 8;
    float4 qa = *(const float4*)qp, qb4 = *(const float4*)(qp + 4);
    float qv[8] = {qa.x, qa.y, qa.z, qa.w, qb4.x, qb4.y, qb4.z, qb4.w};
    float acc[8] = {0,0,0,0,0,0,0,0};
    const bf16* kbase = kk + (size_t)b * S_ * D_ + lane * 8;
    const bf16* vbase = vv + (size_t)b * S_ * D_ + lane * 8;
    for (int s = w; s < slen; s += 4) {
        union { uint4 u; bf16 h[8]; } kl, vl;
        kl.u = *(const uint4*)(kbase + (size_t)s * D_);
        float part = 0.f;
#pragma unroll
        for (int j = 0; j < 8; ++j) part += qv[j] * __bfloat162float(kl.h[j]);
        part += __shfl_xor(part, 1);
        part += __shfl_xor(part, 2);
        part += __shfl_xor(part, 4);   // 8-lane group: full 64-dim head dot
        float p = 1.f / (1.f + __expf(-part * 0.125f));
        vl.u = *(const uint4*)(vbase + (size_t)s * D_);
#pragma unroll
        for (int j = 0; j < 8; ++j) acc[j] += p * __bfloat162float(vl.h[j]);
    }
    __shared__ float macc[4][D_];
#pragma unroll
    for (int j = 0; j < 8; ++j) macc[w][lane * 8 + j] = acc[j];
    __syncthreads();
    __shared__ float red[256];
    int d1 = t + 256;
    float x0 = macc[0][t] + macc[1][t] + macc[2][t] + macc[3][t];
    float x1 = macc[0][d1] + macc[1][d1] + macc[2][d1] + macc[3][d1];
    red[t] = x0 + x1; __syncthreads();
    for (int st = 128; st; st >>= 1) {
        if (t < st) red[t] += red[t + st];
        __syncthreads();
    }
    float mean = red[0] * (1.f / 512.f); __syncthreads();
    float c0 = x0 - mean, c1 = x1 - mean;
    red[t] = c0 * c0 + c1 * c1; __syncthreads();
    for (int st = 128; st; st >>= 1) {
        if (t < st) red[t] += red[t + st];
        __syncthreads();
    }
    float rstd = rsqrtf(red[0] * (1.f / 512.f) + 1e-5f);
    float y0 = c0 * rstd * lng_g[t] + lng_b[t];
    float y1 = c1 * rstd * lng_g[d1] + lng_b[d1];
    mf[(size_t)b * D_ + t] = y0;
    mf[(size_t)b * D_ + d1] = y1;
    mb[(size_t)b * D_ + t] = __float2bfloat16(y0);
    mb[(size_t)b * D_ + d1] = __float2bfloat16(y1);
}

// ---------------- GRU elementwise update ----------------
__global__ void __launch_bounds__(256) k_gru(
        const float* __restrict__ gi, const float* __restrict__ gh,
        float* __restrict__ bt, bf16* __restrict__ btb) {
    int i = blockIdx.x * 256 + threadIdx.x;
    int b = i >> 9, d = i & 511;
    const float* gib = gi + (size_t)b * TD_;
    const float* ghb = gh + (size_t)b * TD_;
    float ir = gib[d], iz = gib[512 + d], inn = gib[1024 + d];
    float hr = ghb[d], hz = ghb[512 + d], hn = ghb[1024 + d];
    float r = 1.f / (1.f + expf(-(ir + hr)));
    float z = 1.f / (1.f + expf(-(iz + hz)));
    float n = tanhf(inn + r * hn);
    float bo = bt[i];
    float bn = (1.f - z) * n + z * bo;
    bt[i] = bn;
    btb[i] = __float2bfloat16(bn);
}

// ---------------- launch ----------------
extern "C" void kernel_launch(void* const* d_in, const int* in_sizes, int n_in,
                              void* d_out, int out_size, void* d_ws, size_t ws_size,
                              hipStream_t stream) {
    const float* emb   = (const float*)d_in[0];
    const int*   stc   = (const int*)d_in[1];
    const int*   offs  = (const int*)d_in[2];
    const int*   sep   = (const int*)d_in[3];
    const float* W1    = (const float*)d_in[4];
    const float* W2    = (const float*)d_in[5];
    const float* ln_g  = (const float*)d_in[6];
    const float* ln_b  = (const float*)d_in[7];
    const float* lng_g = (const float*)d_in[8];
    const float* lng_b = (const float*)d_in[9];
    const float* Wq    = (const float*)d_in[10];
    const float* bq    = (const float*)d_in[11];
    const float* Wk    = (const float*)d_in[12];
    const float* bk    = (const float*)d_in[13];
    const float* Wv    = (const float*)d_in[14];
    const float* bv    = (const float*)d_in[15];
    const float* W_ih  = (const float*)d_in[16];
    const float* W_hh  = (const float*)d_in[17];
    const float* b_ih  = (const float*)d_in[18];
    const float* b_hh  = (const float*)d_in[19];
    const float* seg_e = (const float*)d_in[20];
    const float* pe    = (const float*)d_in[21];

    char* base = (char*)d_ws;
    size_t off = 0;
    auto alloc = [&](size_t bytes) -> void* {
        off = (off + 255) & ~(size_t)255;
        void* r = base + off;
        off += bytes;
        return r;
    };
    bf16* kvk = (bf16*)alloc((size_t)(B_ * S_ + 64) * D_ * 2);
    bf16* kvv = (bf16*)alloc((size_t)(B_ * S_ + 64) * D_ * 2);
    float* hblk = (float*)alloc((size_t)B_ * LBLK * D_ * 4);
    float* a_s  = (float*)alloc((size_t)B_ * 4 * 4);
    float* scr  = (float*)alloc((size_t)B_ * 4 * 4);
    int*   se   = (int*)alloc((size_t)B_ * 2 * 4);
    float* bt   = (float*)alloc((size_t)B_ * D_ * 4);
    bf16*  btb  = (bf16*)alloc((size_t)B_ * D_ * 2);
    float* qb   = (float*)alloc((size_t)B_ * D_ * 4);
    float* mf   = (float*)alloc((size_t)B_ * D_ * 4);
    bf16*  mb   = (bf16*)alloc((size_t)B_ * D_ * 2);
    float* gi   = (float*)alloc((size_t)B_ * TD_ * 4);
    float* gh   = (float*)alloc((size_t)B_ * TD_ * 4);
    bf16* Wq_b  = (bf16*)alloc((size_t)D_ * D_ * 2);
    bf16* Wk_b  = (bf16*)alloc((size_t)D_ * D_ * 2);
    bf16* Wv_b  = (bf16*)alloc((size_t)D_ * D_ * 2);
    bf16* WihT  = (bf16*)alloc((size_t)D_ * TD_ * 2);
    bf16* WhhT  = (bf16*)alloc((size_t)D_ * TD_ * 2);

    // choose H staging chunk size by remaining workspace
    auto hbytes = [](int ch) { return ((size_t)ch * S_ + 64) * D_ * 2; };
    int CH = 512;
    {
        size_t used = (off + 255) & ~(size_t)255;
        size_t remain = (ws_size > used) ? (ws_size - used) : 0;
        if (hbytes(512) + 256 > remain) CH = 64;
        if (CH == 64 && hbytes(64) + 256 > remain) CH = 16;
    }
    bf16* Hc = (bf16*)alloc(hbytes(CH));

    // weight prep
    k_cvt<<<(D_ * D_ + 255) / 256, 256, 0, stream>>>(Wq, Wq_b, D_ * D_);
    k_cvt<<<(D_ * D_ + 255) / 256, 256, 0, stream>>>(Wk, Wk_b, D_ * D_);
    k_cvt<<<(D_ * D_ + 255) / 256, 256, 0, stream>>>(Wv, Wv_b, D_ * D_);
    k_tcvt<<<(D_ * TD_ + 255) / 256, 256, 0, stream>>>(W_ih, WihT);
    k_tcvt<<<(D_ * TD_ + 255) / 256, 256, 0, stream>>>(W_hh, WhhT);

    // block-score path -> b_t init
    k_blockscore<<<B_, 256, 0, stream>>>(emb, W1, W2, stc, offs, sep, hblk, a_s, se);
    k_score<<<1, 512, 0, stream>>>(a_s, se, scr);
    k_b0<<<B_, 64, 0, stream>>>(hblk, scr, pe, ln_g, ln_b, bt, btb);

    // H -> kproj/vproj (chunked over batches)
    for (int c = 0; c < B_; c += CH) {
        int rows = CH * S_;
        k_H<<<(rows + 3) / 4, 256, 0, stream>>>(emb, pe, seg_e, ln_g, ln_b,
                                                stc, offs, Hc, c, rows);
        k_gemm_kv<<<dim3(16, 4, CH), 256, 0, stream>>>(Hc, Wk_b, Wv_b, bk, bv,
                                                       kvk, kvv, stc, c);
    }

    // 3 GRU iterations
    for (int it = 0; it < NITER; ++it) {
        k_gemm_flat<<<dim3(8, 8), 256, 0, stream>>>(btb, D_, Wq_b, D_, bq,
                                                    qb, nullptr, D_);
        k_attn<<<B_, 256, 0, stream>>>(qb, kvk, kvv, stc, lng_g, lng_b, mf, mb);
        k_gemm_flat<<<dim3(24, 8), 256, 0, stream>>>(mb, D_, WihT, TD_, b_ih,
                                                     gi, nullptr, TD_);
        k_gemm_flat<<<dim3(24, 8), 256, 0, stream>>>(btb, D_, WhhT, TD_, b_hh,
                                                     gh, nullptr, TD_);
        k_gru<<<(B_ * D_) / 256, 256, 0, stream>>>(gi, gh, bt, btb);
    }
    hipMemcpyAsync(d_out, bt, (size_t)out_size * sizeof(float),
                   hipMemcpyDeviceToDevice, stream);
}

// Round 4
// 783.206 us; speedup vs baseline: 1.0778x; 1.0778x over previous
//
#include <hip/hip_runtime.h>
#include <hip/hip_bf16.h>
#include <math.h>

// Problem constants
constexpr int B_   = 512;
constexpr int S_   = 200;
constexpr int D_   = 512;
constexpr int LBLK = 4;     // 2*K
constexpr int NITER = 3;
constexpr int TD_  = 1536;  // 3*D
#define NEGV (-1000000000.0f)

using bf16 = __hip_bfloat16;
typedef __attribute__((ext_vector_type(8))) short bf16x8;
typedef __attribute__((ext_vector_type(4))) float f32x4;

__device__ __forceinline__ float wred(float x) {
#pragma unroll
    for (int o = 32; o; o >>= 1) x += __shfl_xor(x, o);
    return x;
}

// async global->LDS 16B (dest must be wave-uniform base; HW writes base+lane*16)
__device__ __forceinline__ void gload16(const bf16* g, bf16* l) {
    __builtin_amdgcn_global_load_lds(
        (const __attribute__((address_space(1))) void*)g,
        (__attribute__((address_space(3))) void*)l, 16, 0, 0);
}

// ---------------- prep: weight layout conversion (one launch) ----------------
// WqT[n][k] = Wq[k][n]; WkvT[n][k] = (n<512?Wk:Wv)[k][n%512]; Wih/Whh straight cvt
__global__ void __launch_bounds__(256) k_prep(
        const float* __restrict__ Wq, const float* __restrict__ Wk,
        const float* __restrict__ Wv, const float* __restrict__ bk,
        const float* __restrict__ bv, const float* __restrict__ Wih,
        const float* __restrict__ Whh, bf16* __restrict__ WqT,
        bf16* __restrict__ WkvT, float* __restrict__ bkv,
        bf16* __restrict__ Wih_b, bf16* __restrict__ Whh_b) {
    int i = blockIdx.x * 256 + threadIdx.x;
    if (i < 512 * 512) {
        int n = i >> 9, k = i & 511;
        WqT[i] = __float2bfloat16(Wq[k * 512 + n]);
        return;
    }
    i -= 512 * 512;
    if (i < 1024 * 512) {
        int n = i >> 9, k = i & 511;
        WkvT[i] = __float2bfloat16(n < 512 ? Wk[k * 512 + n]
                                           : Wv[k * 512 + (n - 512)]);
        return;
    }
    i -= 1024 * 512;
    if (i < TD_ * D_) { Wih_b[i] = __float2bfloat16(Wih[i]); return; }
    i -= TD_ * D_;
    if (i < TD_ * D_) { Whh_b[i] = __float2bfloat16(Whh[i]); return; }
    i -= TD_ * D_;
    if (i < 1024) bkv[i] = (i < 512) ? bk[i] : bv[i - 512];
}

// ---------------- stage 1: h_blk + a = tanh(h_blk@W1)@W2 ----------------
__global__ void __launch_bounds__(256) k_blockscore(
        const float* __restrict__ emb, const float* __restrict__ W1,
        const float* __restrict__ W2, const int* __restrict__ stc,
        const int* __restrict__ offs, const int* __restrict__ sep,
        float* __restrict__ hblk, float* __restrict__ a_out,
        int* __restrict__ se_out) {
    int b = blockIdx.x;
    int t = threadIdx.x;
    int off = offs[b], slen = stc[b];
    int sA = sep[b * 2 + 0], sB = sep[b * 2 + 1];
    int idx = (sA < off ? 1 : 0) + (sB < off ? 1 : 0);
    int prev = (idx == 2) ? sB : sA;
    int nxt  = (idx == 0) ? sA : sB;
    int left = (idx > 0) ? prev + 1 : 0;
    int right = (idx < 2) ? nxt : slen;
    int start = max(off - 2, left);
    int end   = min(off + 2, right);

    __shared__ float hs[LBLK][D_];
    {
        int l = t >> 6, lane = t & 63;
        int ind = start + l;
        bool valid = ind < end;
        float v0x=0,v0y=0,v0z=0,v0w=0,v1x=0,v1y=0,v1z=0,v1w=0;
        if (valid) {
            int ic = min(max(ind, 0), S_ - 1);
            const float* src = emb + ((size_t)b * S_ + ic) * D_ + lane * 8;
            float4 u0 = *(const float4*)src;
            float4 u1 = *(const float4*)(src + 4);
            v0x=u0.x; v0y=u0.y; v0z=u0.z; v0w=u0.w;
            v1x=u1.x; v1y=u1.y; v1z=u1.z; v1w=u1.w;
        }
        int base = lane * 8;
        hs[l][base+0]=v0x; hs[l][base+1]=v0y; hs[l][base+2]=v0z; hs[l][base+3]=v0w;
        hs[l][base+4]=v1x; hs[l][base+5]=v1y; hs[l][base+6]=v1z; hs[l][base+7]=v1w;
        float* g = hblk + ((size_t)b * LBLK + l) * D_ + base;
        g[0]=v0x; g[1]=v0y; g[2]=v0z; g[3]=v0w; g[4]=v1x; g[5]=v1y; g[6]=v1z; g[7]=v1w;
    }
    __syncthreads();

    float pa0 = 0.f, pa1 = 0.f, pa2 = 0.f, pa3 = 0.f;
#pragma unroll
    for (int cc = 0; cc < 2; ++cc) {
        int col = t + cc * 256;
        float a0 = 0.f, a1 = 0.f, a2 = 0.f, a3 = 0.f;
        for (int d = 0; d < D_; ++d) {
            float w = W1[(size_t)d * 512 + col];
            a0 += hs[0][d] * w; a1 += hs[1][d] * w;
            a2 += hs[2][d] * w; a3 += hs[3][d] * w;
        }
        float w2 = W2[col];
        pa0 += tanhf(a0) * w2; pa1 += tanhf(a1) * w2;
        pa2 += tanhf(a2) * w2; pa3 += tanhf(a3) * w2;
    }
    __shared__ float red[256];
    float pv[4] = {pa0, pa1, pa2, pa3};
#pragma unroll
    for (int l = 0; l < 4; ++l) {
        red[t] = pv[l]; __syncthreads();
        for (int st = 128; st; st >>= 1) {
            if (t < st) red[t] += red[t + st];
            __syncthreads();
        }
        if (t == 0) a_out[b * 4 + l] = red[0];
        __syncthreads();
    }
    if (t == 0) { se_out[b * 2] = start; se_out[b * 2 + 1] = end; }
}

// ---------------- stage 2: cross-batch softmax + masked row softmax ----------------
__global__ void __launch_bounds__(512) k_score(const float* __restrict__ a_in,
                                               const int* __restrict__ se,
                                               float* __restrict__ score) {
    int b = threadIdx.x;  // 512 threads, 1 block
    float av[4], s1[4];
#pragma unroll
    for (int l = 0; l < 4; ++l) av[l] = a_in[b * 4 + l];
    __shared__ float red[512];
#pragma unroll
    for (int l = 0; l < 4; ++l) {
        red[b] = av[l]; __syncthreads();
        for (int st = 256; st; st >>= 1) {
            if (b < st) red[b] = fmaxf(red[b], red[b + st]);
            __syncthreads();
        }
        float mx = red[0]; __syncthreads();
        float e = expf(av[l] - mx);
        red[b] = e; __syncthreads();
        for (int st = 256; st; st >>= 1) {
            if (b < st) red[b] += red[b + st];
            __syncthreads();
        }
        s1[l] = e / red[0];
        __syncthreads();
    }
    int start = se[b * 2], end = se[b * 2 + 1];
    float x[4], mx2 = -1e30f;
#pragma unroll
    for (int l = 0; l < 4; ++l) {
        x[l] = (start + l < end) ? s1[l] : NEGV;
        mx2 = fmaxf(mx2, x[l]);
    }
    float s = 0.f, e4[4];
#pragma unroll
    for (int l = 0; l < 4; ++l) { e4[l] = expf(x[l] - mx2); s += e4[l]; }
    float inv = 1.f / s;
#pragma unroll
    for (int l = 0; l < 4; ++l) score[b * 4 + l] = e4[l] * inv;
}

// ---------------- stage 3: b0 = score . h_blk, + pe[0], LN -> b_t ----------------
__global__ void __launch_bounds__(64) k_b0(
        const float* __restrict__ hblk, const float* __restrict__ score,
        const float* __restrict__ pe, const float* __restrict__ g,
        const float* __restrict__ bb, float* __restrict__ bt,
        bf16* __restrict__ btb) {
    int b = blockIdx.x, lane = threadIdx.x;
    float sc0 = score[b*4+0], sc1 = score[b*4+1], sc2 = score[b*4+2], sc3 = score[b*4+3];
    const float* hb = hblk + (size_t)b * LBLK * D_ + lane * 8;
    float v[8];
#pragma unroll
    for (int j = 0; j < 8; ++j) {
        float x = pe[lane * 8 + j];
        x += sc0 * hb[j] + sc1 * hb[D_ + j] + sc2 * hb[2*D_ + j] + sc3 * hb[3*D_ + j];
        v[j] = x;
    }
    float sum = 0.f;
#pragma unroll
    for (int j = 0; j < 8; ++j) sum += v[j];
    sum = wred(sum);
    float mean = sum * (1.f / 512.f);
    float sq = 0.f;
#pragma unroll
    for (int j = 0; j < 8; ++j) { float c = v[j] - mean; sq += c * c; }
    sq = wred(sq);
    float rstd = rsqrtf(sq * (1.f / 512.f) + 1e-5f);
#pragma unroll
    for (int j = 0; j < 8; ++j) {
        int d = lane * 8 + j;
        float y = (v[j] - mean) * rstd * g[d] + bb[d];
        bt[(size_t)b * D_ + d] = y;
        btb[(size_t)b * D_ + d] = __float2bfloat16(y);
    }
}

// ---------------- stage 4: H = LN(emb + pe[ip] + seg_emb[seg]) -> bf16 ----------------
__global__ void __launch_bounds__(256) k_H(
        const float* __restrict__ emb, const float* __restrict__ pe,
        const float* __restrict__ seg_emb, const float* __restrict__ g,
        const float* __restrict__ bb, const int* __restrict__ stc,
        const int* __restrict__ offs, bf16* __restrict__ Hc,
        int b0, int nrows) {
    int rid = blockIdx.x * 4 + (threadIdx.x >> 6);
    if (rid >= nrows) return;
    int lane = threadIdx.x & 63;
    int bl = rid / S_;
    int s = rid - bl * S_;
    int b = b0 + bl;
    int slen = stc[b];
    if (s >= slen) return;
    int pos = offs[b];
    int ip = (s < pos) ? (pos - s) : (s + 1 - pos);
    if (ip > S_) ip = S_;
    int seg = (s >= pos) ? 1 : 0;
    const float* er = emb + ((size_t)b * S_ + s) * D_ + lane * 8;
    const float* pr = pe + (size_t)ip * D_ + lane * 8;
    const float* sr = seg_emb + seg * D_ + lane * 8;
    float4 e0 = *(const float4*)er, e1 = *(const float4*)(er + 4);
    float4 p0 = *(const float4*)pr, p1 = *(const float4*)(pr + 4);
    float4 q0 = *(const float4*)sr, q1 = *(const float4*)(sr + 4);
    float v[8];
    v[0]=e0.x+p0.x+q0.x; v[1]=e0.y+p0.y+q0.y; v[2]=e0.z+p0.z+q0.z; v[3]=e0.w+p0.w+q0.w;
    v[4]=e1.x+p1.x+q1.x; v[5]=e1.y+p1.y+q1.y; v[6]=e1.z+p1.z+q1.z; v[7]=e1.w+p1.w+q1.w;
    float sum = 0.f;
#pragma unroll
    for (int j = 0; j < 8; ++j) sum += v[j];
    sum = wred(sum);
    float mean = sum * (1.f / 512.f);
    float sq = 0.f;
#pragma unroll
    for (int j = 0; j < 8; ++j) { float c = v[j] - mean; sq += c * c; }
    sq = wred(sq);
    float rstd = rsqrtf(sq * (1.f / 512.f) + 1e-5f);
    union { uint4 u; bf16 h[8]; } o;
#pragma unroll
    for (int j = 0; j < 8; ++j) {
        int d = lane * 8 + j;
        o.h[j] = __float2bfloat16((v[j] - mean) * rstd * g[d] + bb[d]);
    }
    *(uint4*)(Hc + ((size_t)bl * S_ + s) * D_ + lane * 8) = o.u;
}

// ---------------- MFMA GEMM core: A row-major (M x 512), B in N-major (N x 512) ----
// K fixed at 512, BK=32. global_load_lds staging (linear LDS, 16B/lane).
// BM,BN: block tile. NWM x NWN: wave grid (NWM*NWN*64 threads).
template<int BM, int BN, int NWM, int NWN, bool OUT_BF16>
__device__ __forceinline__ void gemm_core(
        const bf16* __restrict__ A, int lda,
        const bf16* __restrict__ Bnk, int ldb,
        const float* __restrict__ bias,
        void* __restrict__ Cout, int ldc, int rows_valid) {
    constexpr int NW = NWM * NWN;
    constexpr int FM = BM / (NWM * 16);
    constexpr int FN = BN / (NWN * 16);
    constexpr int IA = BM / (16 * NW);   // A stage wave-instrs per wave
    constexpr int IB = BN / (16 * NW);   // B stage wave-instrs per wave
    __shared__ bf16 As[BM * 32];
    __shared__ bf16 Bs[BN * 32];
    int t = threadIdx.x, lane = t & 63, w = t >> 6;
    int wm = w / NWN, wn = w % NWN;
    int sr = lane >> 2;           // staged row within 16-row group
    int sc = (lane & 3) * 8;      // staged k-col (elements)

    f32x4 acc[FM][FN];
#pragma unroll
    for (int i = 0; i < FM; ++i)
#pragma unroll
        for (int j = 0; j < FN; ++j) acc[i][j] = f32x4{0.f,0.f,0.f,0.f};

    for (int k0 = 0; k0 < 512; k0 += 32) {
#pragma unroll
        for (int j = 0; j < IA; ++j) {
            int r = (w * IA + j) * 16 + sr;
            gload16(A + (size_t)r * lda + k0 + sc, &As[(w * IA + j) * 512]);
        }
#pragma unroll
        for (int j = 0; j < IB; ++j) {
            int r = (w * IB + j) * 16 + sr;
            gload16(Bnk + (size_t)r * ldb + k0 + sc, &Bs[(w * IB + j) * 512]);
        }
        __syncthreads();
        bf16x8 af[FM], bfr[FN];
#pragma unroll
        for (int i = 0; i < FM; ++i)
            af[i] = *(const bf16x8*)&As[((wm * FM + i) * 16 + (lane & 15)) * 32
                                        + (lane >> 4) * 8];
#pragma unroll
        for (int j = 0; j < FN; ++j)
            bfr[j] = *(const bf16x8*)&Bs[((wn * FN + j) * 16 + (lane & 15)) * 32
                                         + (lane >> 4) * 8];
#pragma unroll
        for (int i = 0; i < FM; ++i)
#pragma unroll
            for (int j = 0; j < FN; ++j)
                acc[i][j] = __builtin_amdgcn_mfma_f32_16x16x32_bf16(
                                af[i], bfr[j], acc[i][j], 0, 0, 0);
        __syncthreads();
    }
    // C/D: col = lane&15 (N), row = (lane>>4)*4 + rr (M)
    int coln = wn * FN * 16 + (lane & 15);
    int rowb = (lane >> 4) * 4;
#pragma unroll
    for (int j = 0; j < FN; ++j) {
        int col = coln + j * 16;
        float bvv = bias[col];
#pragma unroll
        for (int i = 0; i < FM; ++i) {
            int rbase = (wm * FM + i) * 16 + rowb;
#pragma unroll
            for (int rr = 0; rr < 4; ++rr) {
                int row = rbase + rr;
                if (row < rows_valid) {
                    float v = acc[i][j][rr] + bvv;
                    if (OUT_BF16)
                        ((bf16*)Cout)[(size_t)row * ldc + col] = __float2bfloat16(v);
                    else
                        ((float*)Cout)[(size_t)row * ldc + col] = v;
                }
            }
        }
    }
}

// fused K+V projection: C = Hc @ WkvT^T + bkv -> kv[b][s][1024]
__global__ void __launch_bounds__(256) k_gemm_kv2(
        const bf16* __restrict__ Hc, const bf16* __restrict__ WkvT,
        const float* __restrict__ bkv, bf16* __restrict__ kv,
        const int* __restrict__ stc, int b0) {
    int bl = blockIdx.z;
    int b = b0 + bl;
    int s0 = blockIdx.y * 64;
    int slen = stc[b];
    if (s0 >= slen) return;
    int n0 = blockIdx.x * 256;
    gemm_core<64, 256, 1, 4, true>(
        Hc + ((size_t)bl * S_ + s0) * D_, D_,
        WkvT + (size_t)n0 * 512, 512, bkv + n0,
        kv + ((size_t)b * S_ + s0) * 1024 + n0, 1024,
        min(64, slen - s0));
}

// q = btb @ WqT^T + bq (f32 out)
__global__ void __launch_bounds__(256) k_gemm_q(
        const bf16* __restrict__ btb, const bf16* __restrict__ WqT,
        const float* __restrict__ bq, float* __restrict__ qb) {
    int n0 = blockIdx.x * 64, m0 = blockIdx.y * 64;
    gemm_core<64, 64, 2, 2, false>(
        btb + (size_t)m0 * D_, D_, WqT + (size_t)n0 * 512, 512, bq + n0,
        qb + (size_t)m0 * D_ + n0, D_, 64);
}

// gi = mb @ Wih^T + b_ih  (z=0)  /  gh = btb @ Whh^T + b_hh  (z=1)
__global__ void __launch_bounds__(256) k_gemm_gates(
        const bf16* __restrict__ mb, const bf16* __restrict__ btb,
        const bf16* __restrict__ Wih_b, const bf16* __restrict__ Whh_b,
        const float* __restrict__ b_ih, const float* __restrict__ b_hh,
        float* __restrict__ gi, float* __restrict__ gh) {
    int n0 = blockIdx.x * 128, m0 = blockIdx.y * 64;
    const bf16* A  = blockIdx.z ? btb : mb;
    const bf16* Bm = blockIdx.z ? Whh_b : Wih_b;
    const float* bias = blockIdx.z ? b_hh : b_ih;
    float* C = blockIdx.z ? gh : gi;
    gemm_core<64, 128, 2, 2, false>(
        A + (size_t)m0 * D_, D_, Bm + (size_t)n0 * 512, 512, bias + n0,
        C + (size_t)m0 * TD_ + n0, TD_, 64);
}

// ---------------- attention + LN(m_t) ----------------
__global__ void __launch_bounds__(256) k_attn(
        const float* __restrict__ q, const bf16* __restrict__ kv,
        const int* __restrict__ stc, const float* __restrict__ lng_g,
        const float* __restrict__ lng_b, float* __restrict__ mf,
        bf16* __restrict__ mb) {
    int b = blockIdx.x;
    int t = threadIdx.x, w = t >> 6, lane = t & 63;
    int slen = stc[b];
    const float* qp = q + (size_t)b * D_ + lane * 8;
    float4 qa = *(const float4*)qp, qb4 = *(const float4*)(qp + 4);
    float qv[8] = {qa.x, qa.y, qa.z, qa.w, qb4.x, qb4.y, qb4.z, qb4.w};
    float acc[8] = {0,0,0,0,0,0,0,0};
    const bf16* kvb = kv + (size_t)b * S_ * 1024 + lane * 8;
    for (int s = w; s < slen; s += 4) {
        union { uint4 u; bf16 h[8]; } kl, vl;
        kl.u = *(const uint4*)(kvb + (size_t)s * 1024);
        float part = 0.f;
#pragma unroll
        for (int j = 0; j < 8; ++j) part += qv[j] * __bfloat162float(kl.h[j]);
        part += __shfl_xor(part, 1);
        part += __shfl_xor(part, 2);
        part += __shfl_xor(part, 4);   // 8-lane group: full 64-dim head dot
        float p = 1.f / (1.f + __expf(-part * 0.125f));
        vl.u = *(const uint4*)(kvb + (size_t)s * 1024 + 512);
#pragma unroll
        for (int j = 0; j < 8; ++j) acc[j] += p * __bfloat162float(vl.h[j]);
    }
    __shared__ float macc[4][D_];
#pragma unroll
    for (int j = 0; j < 8; ++j) macc[w][lane * 8 + j] = acc[j];
    __syncthreads();
    __shared__ float red[256];
    int d1 = t + 256;
    float x0 = macc[0][t] + macc[1][t] + macc[2][t] + macc[3][t];
    float x1 = macc[0][d1] + macc[1][d1] + macc[2][d1] + macc[3][d1];
    red[t] = x0 + x1; __syncthreads();
    for (int st = 128; st; st >>= 1) {
        if (t < st) red[t] += red[t + st];
        __syncthreads();
    }
    float mean = red[0] * (1.f / 512.f); __syncthreads();
    float c0 = x0 - mean, c1 = x1 - mean;
    red[t] = c0 * c0 + c1 * c1; __syncthreads();
    for (int st = 128; st; st >>= 1) {
        if (t < st) red[t] += red[t + st];
        __syncthreads();
    }
    float rstd = rsqrtf(red[0] * (1.f / 512.f) + 1e-5f);
    float y0 = c0 * rstd * lng_g[t] + lng_b[t];
    float y1 = c1 * rstd * lng_g[d1] + lng_b[d1];
    mf[(size_t)b * D_ + t] = y0;
    mf[(size_t)b * D_ + d1] = y1;
    mb[(size_t)b * D_ + t] = __float2bfloat16(y0);
    mb[(size_t)b * D_ + d1] = __float2bfloat16(y1);
}

// ---------------- GRU elementwise update ----------------
__global__ void __launch_bounds__(256) k_gru(
        const float* __restrict__ gi, const float* __restrict__ gh,
        float* __restrict__ bt, bf16* __restrict__ btb) {
    int i = blockIdx.x * 256 + threadIdx.x;
    int b = i >> 9, d = i & 511;
    const float* gib = gi + (size_t)b * TD_;
    const float* ghb = gh + (size_t)b * TD_;
    float ir = gib[d], iz = gib[512 + d], inn = gib[1024 + d];
    float hr = ghb[d], hz = ghb[512 + d], hn = ghb[1024 + d];
    float r = 1.f / (1.f + expf(-(ir + hr)));
    float z = 1.f / (1.f + expf(-(iz + hz)));
    float n = tanhf(inn + r * hn);
    float bo = bt[i];
    float bn = (1.f - z) * n + z * bo;
    bt[i] = bn;
    btb[i] = __float2bfloat16(bn);
}

// ---------------- launch ----------------
extern "C" void kernel_launch(void* const* d_in, const int* in_sizes, int n_in,
                              void* d_out, int out_size, void* d_ws, size_t ws_size,
                              hipStream_t stream) {
    const float* emb   = (const float*)d_in[0];
    const int*   stc   = (const int*)d_in[1];
    const int*   offs  = (const int*)d_in[2];
    const int*   sep   = (const int*)d_in[3];
    const float* W1    = (const float*)d_in[4];
    const float* W2    = (const float*)d_in[5];
    const float* ln_g  = (const float*)d_in[6];
    const float* ln_b  = (const float*)d_in[7];
    const float* lng_g = (const float*)d_in[8];
    const float* lng_b = (const float*)d_in[9];
    const float* Wq    = (const float*)d_in[10];
    const float* bq    = (const float*)d_in[11];
    const float* Wk    = (const float*)d_in[12];
    const float* bk    = (const float*)d_in[13];
    const float* Wv    = (const float*)d_in[14];
    const float* bv    = (const float*)d_in[15];
    const float* W_ih  = (const float*)d_in[16];
    const float* W_hh  = (const float*)d_in[17];
    const float* b_ih  = (const float*)d_in[18];
    const float* b_hh  = (const float*)d_in[19];
    const float* seg_e = (const float*)d_in[20];
    const float* pe    = (const float*)d_in[21];

    char* base = (char*)d_ws;
    size_t off = 0;
    auto alloc = [&](size_t bytes) -> void* {
        off = (off + 255) & ~(size_t)255;
        void* r = base + off;
        off += bytes;
        return r;
    };
    bf16* kv   = (bf16*)alloc(((size_t)B_ * S_ + 64) * 1024 * 2);   // fused K|V
    float* hblk = (float*)alloc((size_t)B_ * LBLK * D_ * 4);
    float* a_s  = (float*)alloc((size_t)B_ * 4 * 4);
    float* scr  = (float*)alloc((size_t)B_ * 4 * 4);
    int*   se   = (int*)alloc((size_t)B_ * 2 * 4);
    float* bt   = (float*)alloc((size_t)B_ * D_ * 4);
    bf16*  btb  = (bf16*)alloc((size_t)B_ * D_ * 2);
    float* qb   = (float*)alloc((size_t)B_ * D_ * 4);
    float* mf   = (float*)alloc((size_t)B_ * D_ * 4);
    bf16*  mb   = (bf16*)alloc((size_t)B_ * D_ * 2);
    float* gi   = (float*)alloc((size_t)B_ * TD_ * 4);
    float* gh   = (float*)alloc((size_t)B_ * TD_ * 4);
    bf16* WqT   = (bf16*)alloc((size_t)D_ * D_ * 2);
    bf16* WkvT  = (bf16*)alloc((size_t)1024 * 512 * 2);
    float* bkv  = (float*)alloc((size_t)1024 * 4);
    bf16* Wih_b = (bf16*)alloc((size_t)TD_ * D_ * 2);
    bf16* Whh_b = (bf16*)alloc((size_t)TD_ * D_ * 2);

    // choose H staging chunk size by remaining workspace
    auto hbytes = [](int ch) { return ((size_t)ch * S_ + 64) * D_ * 2; };
    int CH = 512;
    {
        size_t used = (off + 255) & ~(size_t)255;
        size_t remain = (ws_size > used) ? (ws_size - used) : 0;
        if (hbytes(512) + 256 > remain) CH = 64;
        if (CH == 64 && hbytes(64) + 256 > remain) CH = 16;
    }
    bf16* Hc = (bf16*)alloc(hbytes(CH));

    // weight prep (single launch)
    {
        int total = 512*512 + 1024*512 + 2*TD_*D_ + 1024;
        k_prep<<<(total + 255) / 256, 256, 0, stream>>>(
            Wq, Wk, Wv, bk, bv, W_ih, W_hh, WqT, WkvT, bkv, Wih_b, Whh_b);
    }

    // block-score path -> b_t init
    k_blockscore<<<B_, 256, 0, stream>>>(emb, W1, W2, stc, offs, sep, hblk, a_s, se);
    k_score<<<1, 512, 0, stream>>>(a_s, se, scr);
    k_b0<<<B_, 64, 0, stream>>>(hblk, scr, pe, ln_g, ln_b, bt, btb);

    // H -> fused K/V projection (chunked over batches)
    for (int c = 0; c < B_; c += CH) {
        int rows = CH * S_;
        k_H<<<(rows + 3) / 4, 256, 0, stream>>>(emb, pe, seg_e, ln_g, ln_b,
                                                stc, offs, Hc, c, rows);
        k_gemm_kv2<<<dim3(4, 4, CH), 256, 0, stream>>>(Hc, WkvT, bkv, kv, stc, c);
    }

    // 3 GRU iterations
    for (int it = 0; it < NITER; ++it) {
        k_gemm_q<<<dim3(8, 8), 256, 0, stream>>>(btb, WqT, bq, qb);
        k_attn<<<B_, 256, 0, stream>>>(qb, kv, stc, lng_g, lng_b, mf, mb);
        k_gemm_gates<<<dim3(12, 8, 2), 256, 0, stream>>>(mb, btb, Wih_b, Whh_b,
                                                         b_ih, b_hh, gi, gh);
        k_gru<<<(B_ * D_) / 256, 256, 0, stream>>>(gi, gh, bt, btb);
    }
    hipMemcpyAsync(d_out, bt, (size_t)out_size * sizeof(float),
                   hipMemcpyDeviceToDevice, stream);
}

// Round 6
// 717.012 us; speedup vs baseline: 1.1773x; 1.0923x over previous
//
#include <hip/hip_runtime.h>
#include <hip/hip_bf16.h>
#include <math.h>

// Problem constants
constexpr int B_   = 512;
constexpr int S_   = 200;
constexpr int D_   = 512;
constexpr int LBLK = 4;     // 2*K
constexpr int NITER = 3;
constexpr int TD_  = 1536;  // 3*D
#define NEGV (-1000000000.0f)

using bf16 = __hip_bfloat16;
typedef __attribute__((ext_vector_type(8))) short bf16x8;
typedef __attribute__((ext_vector_type(4))) float f32x4;

__device__ __forceinline__ float wred(float x) {
#pragma unroll
    for (int o = 32; o; o >>= 1) x += __shfl_xor(x, o);
    return x;
}

// async global->LDS 16B (dest wave-uniform base; HW writes base+lane*16)
__device__ __forceinline__ void gload16(const bf16* g, bf16* l) {
    __builtin_amdgcn_global_load_lds(
        (const __attribute__((address_space(1))) void*)g,
        (__attribute__((address_space(3))) void*)l, 16, 0, 0);
}

// ---------------- prep: weight layout conversion (one launch) ----------------
__global__ void __launch_bounds__(256) k_prep(
        const float* __restrict__ Wq, const float* __restrict__ Wk,
        const float* __restrict__ Wv, const float* __restrict__ bk,
        const float* __restrict__ bv, const float* __restrict__ Wih,
        const float* __restrict__ Whh, bf16* __restrict__ WqT,
        bf16* __restrict__ WkvT, float* __restrict__ bkv,
        bf16* __restrict__ Wih_b, bf16* __restrict__ Whh_b) {
    int i = blockIdx.x * 256 + threadIdx.x;
    if (i < 512 * 512) {
        int n = i >> 9, k = i & 511;
        WqT[i] = __float2bfloat16(Wq[k * 512 + n]);
        return;
    }
    i -= 512 * 512;
    if (i < 1024 * 512) {
        int n = i >> 9, k = i & 511;
        WkvT[i] = __float2bfloat16(n < 512 ? Wk[k * 512 + n]
                                           : Wv[k * 512 + (n - 512)]);
        return;
    }
    i -= 1024 * 512;
    if (i < TD_ * D_) { Wih_b[i] = __float2bfloat16(Wih[i]); return; }
    i -= TD_ * D_;
    if (i < TD_ * D_) { Whh_b[i] = __float2bfloat16(Whh[i]); return; }
    i -= TD_ * D_;
    if (i < 1024) bkv[i] = (i < 512) ? bk[i] : bv[i - 512];
}

// ---------------- stage 1: h_blk + a = tanh(h_blk@W1)@W2 ----------------
__global__ void __launch_bounds__(256) k_blockscore(
        const float* __restrict__ emb, const float* __restrict__ W1,
        const float* __restrict__ W2, const int* __restrict__ stc,
        const int* __restrict__ offs, const int* __restrict__ sep,
        float* __restrict__ hblk, float* __restrict__ a_out,
        int* __restrict__ se_out) {
    int b = blockIdx.x;
    int t = threadIdx.x;
    int off = offs[b], slen = stc[b];
    int sA = sep[b * 2 + 0], sB = sep[b * 2 + 1];
    int idx = (sA < off ? 1 : 0) + (sB < off ? 1 : 0);
    int prev = (idx == 2) ? sB : sA;
    int nxt  = (idx == 0) ? sA : sB;
    int left = (idx > 0) ? prev + 1 : 0;
    int right = (idx < 2) ? nxt : slen;
    int start = max(off - 2, left);
    int end   = min(off + 2, right);

    __shared__ float hs[LBLK][D_];
    {
        int l = t >> 6, lane = t & 63;
        int ind = start + l;
        bool valid = ind < end;
        float v0x=0,v0y=0,v0z=0,v0w=0,v1x=0,v1y=0,v1z=0,v1w=0;
        if (valid) {
            int ic = min(max(ind, 0), S_ - 1);
            const float* src = emb + ((size_t)b * S_ + ic) * D_ + lane * 8;
            float4 u0 = *(const float4*)src;
            float4 u1 = *(const float4*)(src + 4);
            v0x=u0.x; v0y=u0.y; v0z=u0.z; v0w=u0.w;
            v1x=u1.x; v1y=u1.y; v1z=u1.z; v1w=u1.w;
        }
        int base = lane * 8;
        hs[l][base+0]=v0x; hs[l][base+1]=v0y; hs[l][base+2]=v0z; hs[l][base+3]=v0w;
        hs[l][base+4]=v1x; hs[l][base+5]=v1y; hs[l][base+6]=v1z; hs[l][base+7]=v1w;
        float* g = hblk + ((size_t)b * LBLK + l) * D_ + base;
        g[0]=v0x; g[1]=v0y; g[2]=v0z; g[3]=v0w; g[4]=v1x; g[5]=v1y; g[6]=v1z; g[7]=v1w;
    }
    __syncthreads();

    float pa0 = 0.f, pa1 = 0.f, pa2 = 0.f, pa3 = 0.f;
#pragma unroll
    for (int cc = 0; cc < 2; ++cc) {
        int col = t + cc * 256;
        float a0 = 0.f, a1 = 0.f, a2 = 0.f, a3 = 0.f;
        for (int d = 0; d < D_; ++d) {
            float w = W1[(size_t)d * 512 + col];
            a0 += hs[0][d] * w; a1 += hs[1][d] * w;
            a2 += hs[2][d] * w; a3 += hs[3][d] * w;
        }
        float w2 = W2[col];
        pa0 += tanhf(a0) * w2; pa1 += tanhf(a1) * w2;
        pa2 += tanhf(a2) * w2; pa3 += tanhf(a3) * w2;
    }
    __shared__ float red[256];
    float pv[4] = {pa0, pa1, pa2, pa3};
#pragma unroll
    for (int l = 0; l < 4; ++l) {
        red[t] = pv[l]; __syncthreads();
        for (int st = 128; st; st >>= 1) {
            if (t < st) red[t] += red[t + st];
            __syncthreads();
        }
        if (t == 0) a_out[b * 4 + l] = red[0];
        __syncthreads();
    }
    if (t == 0) { se_out[b * 2] = start; se_out[b * 2 + 1] = end; }
}

// ---------------- stage 2: cross-batch softmax + masked row softmax ----------------
__global__ void __launch_bounds__(512) k_score(const float* __restrict__ a_in,
                                               const int* __restrict__ se,
                                               float* __restrict__ score) {
    int b = threadIdx.x;  // 512 threads, 1 block
    float av[4], s1[4];
#pragma unroll
    for (int l = 0; l < 4; ++l) av[l] = a_in[b * 4 + l];
    __shared__ float red[512];
#pragma unroll
    for (int l = 0; l < 4; ++l) {
        red[b] = av[l]; __syncthreads();
        for (int st = 256; st; st >>= 1) {
            if (b < st) red[b] = fmaxf(red[b], red[b + st]);
            __syncthreads();
        }
        float mx = red[0]; __syncthreads();
        float e = expf(av[l] - mx);
        red[b] = e; __syncthreads();
        for (int st = 256; st; st >>= 1) {
            if (b < st) red[b] += red[b + st];
            __syncthreads();
        }
        s1[l] = e / red[0];
        __syncthreads();
    }
    int start = se[b * 2], end = se[b * 2 + 1];
    float x[4], mx2 = -1e30f;
#pragma unroll
    for (int l = 0; l < 4; ++l) {
        x[l] = (start + l < end) ? s1[l] : NEGV;
        mx2 = fmaxf(mx2, x[l]);
    }
    float s = 0.f, e4[4];
#pragma unroll
    for (int l = 0; l < 4; ++l) { e4[l] = expf(x[l] - mx2); s += e4[l]; }
    float inv = 1.f / s;
#pragma unroll
    for (int l = 0; l < 4; ++l) score[b * 4 + l] = e4[l] * inv;
}

// ---------------- stage 3: b0 = score . h_blk, + pe[0], LN -> b_t ----------------
__global__ void __launch_bounds__(64) k_b0(
        const float* __restrict__ hblk, const float* __restrict__ score,
        const float* __restrict__ pe, const float* __restrict__ g,
        const float* __restrict__ bb, float* __restrict__ bt,
        bf16* __restrict__ btb) {
    int b = blockIdx.x, lane = threadIdx.x;
    float sc0 = score[b*4+0], sc1 = score[b*4+1], sc2 = score[b*4+2], sc3 = score[b*4+3];
    const float* hb = hblk + (size_t)b * LBLK * D_ + lane * 8;
    float v[8];
#pragma unroll
    for (int j = 0; j < 8; ++j) {
        float x = pe[lane * 8 + j];
        x += sc0 * hb[j] + sc1 * hb[D_ + j] + sc2 * hb[2*D_ + j] + sc3 * hb[3*D_ + j];
        v[j] = x;
    }
    float sum = 0.f;
#pragma unroll
    for (int j = 0; j < 8; ++j) sum += v[j];
    sum = wred(sum);
    float mean = sum * (1.f / 512.f);
    float sq = 0.f;
#pragma unroll
    for (int j = 0; j < 8; ++j) { float c = v[j] - mean; sq += c * c; }
    sq = wred(sq);
    float rstd = rsqrtf(sq * (1.f / 512.f) + 1e-5f);
#pragma unroll
    for (int j = 0; j < 8; ++j) {
        int d = lane * 8 + j;
        float y = (v[j] - mean) * rstd * g[d] + bb[d];
        bt[(size_t)b * D_ + d] = y;
        btb[(size_t)b * D_ + d] = __float2bfloat16(y);
    }
}

// ---------------- stage 4: H = LN(emb + pe[ip] + seg_emb[seg]) -> bf16 ----------------
__global__ void __launch_bounds__(256) k_H(
        const float* __restrict__ emb, const float* __restrict__ pe,
        const float* __restrict__ seg_emb, const float* __restrict__ g,
        const float* __restrict__ bb, const int* __restrict__ stc,
        const int* __restrict__ offs, bf16* __restrict__ Hc,
        int b0, int nrows) {
    int rid = blockIdx.x * 4 + (threadIdx.x >> 6);
    if (rid >= nrows) return;
    int lane = threadIdx.x & 63;
    int bl = rid / S_;
    int s = rid - bl * S_;
    int b = b0 + bl;
    int slen = stc[b];
    if (s >= slen) return;
    int pos = offs[b];
    int ip = (s < pos) ? (pos - s) : (s + 1 - pos);
    if (ip > S_) ip = S_;
    int seg = (s >= pos) ? 1 : 0;
    const float* er = emb + ((size_t)b * S_ + s) * D_ + lane * 8;
    const float* pr = pe + (size_t)ip * D_ + lane * 8;
    const float* sr = seg_emb + seg * D_ + lane * 8;
    float4 e0 = *(const float4*)er, e1 = *(const float4*)(er + 4);
    float4 p0 = *(const float4*)pr, p1 = *(const float4*)(pr + 4);
    float4 q0 = *(const float4*)sr, q1 = *(const float4*)(sr + 4);
    float v[8];
    v[0]=e0.x+p0.x+q0.x; v[1]=e0.y+p0.y+q0.y; v[2]=e0.z+p0.z+q0.z; v[3]=e0.w+p0.w+q0.w;
    v[4]=e1.x+p1.x+q1.x; v[5]=e1.y+p1.y+q1.y; v[6]=e1.z+p1.z+q1.z; v[7]=e1.w+p1.w+q1.w;
    float sum = 0.f;
#pragma unroll
    for (int j = 0; j < 8; ++j) sum += v[j];
    sum = wred(sum);
    float mean = sum * (1.f / 512.f);
    float sq = 0.f;
#pragma unroll
    for (int j = 0; j < 8; ++j) { float c = v[j] - mean; sq += c * c; }
    sq = wred(sq);
    float rstd = rsqrtf(sq * (1.f / 512.f) + 1e-5f);
    union { uint4 u; bf16 h[8]; } o;
#pragma unroll
    for (int j = 0; j < 8; ++j) {
        int d = lane * 8 + j;
        o.h[j] = __float2bfloat16((v[j] - mean) * rstd * g[d] + bb[d]);
    }
    *(uint4*)(Hc + ((size_t)bl * S_ + s) * D_ + lane * 8) = o.u;
}

// ---------------- MFMA GEMM core v2 ----------------
// A row-major (M x 512), B N-major (N x 512), K=512, BK=64, double-buffered
// global_load_lds staging with XOR chunk-swizzle (both sides), LDS epilogue.
// 4 waves (NWM=2 x NWN=2), 128x128 tile, FM=FN=4.
template<int BM, int BN, bool OUT_BF16>
__device__ __forceinline__ void gemm_core2(
        const bf16* __restrict__ A, int lda,
        const bf16* __restrict__ Bnk, int ldb,
        const float* __restrict__ bias,
        void* __restrict__ Cout, int ldc, int rows_valid) {
    constexpr int NW = 4, NWN = 2;
    constexpr int FM = BM / 32;          // frags per wave in M (BM/(NWM*16))
    constexpr int FN = BN / 32;
    constexpr int IA = BM / (8 * NW);    // 8-row gload instrs per wave (A)
    constexpr int IB = BN / (8 * NW);
    constexpr int SMEM_B = 2 * (BM + BN) * 64 * 2;   // dbuf staging bytes
    __shared__ char smem[SMEM_B];
    bf16* As = (bf16*)smem;                          // [2][BM*64]
    bf16* Bs = (bf16*)(smem + 2 * BM * 64 * 2);      // [2][BN*64]

    int t = threadIdx.x, lane = t & 63, w = t >> 6;
    int wm = w / NWN, wn = w % NWN;
    int srow = lane >> 3;                       // 0..7 within 8-row group
    int scol = ((lane & 7) ^ srow) * 8;         // swizzled source chunk (elems)
    int fr = lane & 15, q0 = lane >> 4;

    f32x4 acc[FM][FN];
#pragma unroll
    for (int i = 0; i < FM; ++i)
#pragma unroll
        for (int j = 0; j < FN; ++j) acc[i][j] = f32x4{0.f,0.f,0.f,0.f};

    auto STAGE = [&](int buf, int k0) {
#pragma unroll
        for (int jj = 0; jj < IA; ++jj) {
            int g = w * IA + jj;
            gload16(A + (size_t)(g * 8 + srow) * lda + k0 + scol,
                    As + buf * BM * 64 + g * 512);
        }
#pragma unroll
        for (int jj = 0; jj < IB; ++jj) {
            int g = w * IB + jj;
            gload16(Bnk + (size_t)(g * 8 + srow) * ldb + k0 + scol,
                    Bs + buf * BN * 64 + g * 512);
        }
    };
    auto COMPUTE = [&](int buf) {
#pragma unroll
        for (int h = 0; h < 2; ++h) {
            bf16x8 af[FM], bf_[FN];
#pragma unroll
            for (int i = 0; i < FM; ++i) {
                int R = (wm * FM + i) * 16 + fr;
                int slot = (h * 4 + q0) ^ (R & 7);
                af[i] = *(const bf16x8*)&As[buf * BM * 64 + R * 64 + slot * 8];
            }
#pragma unroll
            for (int j = 0; j < FN; ++j) {
                int R = (wn * FN + j) * 16 + fr;
                int slot = (h * 4 + q0) ^ (R & 7);
                bf_[j] = *(const bf16x8*)&Bs[buf * BN * 64 + R * 64 + slot * 8];
            }
#pragma unroll
            for (int i = 0; i < FM; ++i)
#pragma unroll
                for (int j = 0; j < FN; ++j)
                    acc[i][j] = __builtin_amdgcn_mfma_f32_16x16x32_bf16(
                                    af[i], bf_[j], acc[i][j], 0, 0, 0);
        }
    };

    STAGE(0, 0);
    __syncthreads();                 // drain stage-0 loads
    int cur = 0;
#pragma unroll
    for (int kt = 1; kt < 8; ++kt) { // K=512 / BK=64
        STAGE(cur ^ 1, kt * 64);     // prefetch next tile (in flight over compute)
        COMPUTE(cur);
        __syncthreads();             // drains vmcnt(0)+lgkmcnt(0)
        cur ^= 1;
    }
    COMPUTE(cur);
    __syncthreads();                 // protect LDS before epilogue reuse

    // epilogue: acc(+bias) -> LDS tile -> coalesced 16B stores
    constexpr int ESZ = OUT_BF16 ? 2 : 4;
#pragma unroll
    for (int j = 0; j < FN; ++j) {
        int Cc = (wn * FN + j) * 16 + fr;
        float bvv = bias[Cc];
#pragma unroll
        for (int i = 0; i < FM; ++i) {
            int Rb = (wm * FM + i) * 16 + q0 * 4;
#pragma unroll
            for (int rr = 0; rr < 4; ++rr) {
                float v = acc[i][j][rr] + bvv;
                if (OUT_BF16)
                    ((bf16*)smem)[(Rb + rr) * BN + Cc] = __float2bfloat16(v);
                else
                    ((float*)smem)[(size_t)(Rb + rr) * BN + Cc] = v;
            }
        }
    }
    __syncthreads();
    constexpr int CPR = BN * ESZ / 16;          // 16B chunks per row
#pragma unroll 2
    for (int c = t; c < BM * CPR; c += NW * 64) {
        int row = c / CPR, ch = c - row * CPR;
        if (row < rows_valid)
            *(uint4*)((char*)Cout + (size_t)row * ldc * ESZ + ch * 16) =
                *(const uint4*)(smem + (size_t)c * 16);
    }
}

// fused K+V projection: kv[b][s][1024] = Hc @ WkvT^T + bkv
__global__ void __launch_bounds__(256) k_gemm_kv2(
        const bf16* __restrict__ Hc, const bf16* __restrict__ WkvT,
        const float* __restrict__ bkv, bf16* __restrict__ kv,
        const int* __restrict__ stc, int b0) {
    int bl = blockIdx.z;
    int b = b0 + bl;
    int s0 = blockIdx.y * 128;
    int slen = stc[b];
    if (s0 >= slen) return;
    int n0 = blockIdx.x * 128;
    gemm_core2<128, 128, true>(
        Hc + ((size_t)bl * S_ + s0) * D_, D_,
        WkvT + (size_t)n0 * 512, 512, bkv + n0,
        kv + ((size_t)b * S_ + s0) * 1024 + n0, 1024,
        min(128, slen - s0));
}

// q = btb @ WqT^T + bq (f32 out)
__global__ void __launch_bounds__(256) k_gemm_q(
        const bf16* __restrict__ btb, const bf16* __restrict__ WqT,
        const float* __restrict__ bq, float* __restrict__ qb) {
    int n0 = blockIdx.x * 128, m0 = blockIdx.y * 128;
    gemm_core2<128, 128, false>(
        btb + (size_t)m0 * D_, D_, WqT + (size_t)n0 * 512, 512, bq + n0,
        qb + (size_t)m0 * D_ + n0, D_, 128);
}

// gi = mb @ Wih^T + b_ih (z=0) / gh = btb @ Whh^T + b_hh (z=1)
__global__ void __launch_bounds__(256) k_gemm_gates(
        const bf16* __restrict__ mb, const bf16* __restrict__ btb,
        const bf16* __restrict__ Wih_b, const bf16* __restrict__ Whh_b,
        const float* __restrict__ b_ih, const float* __restrict__ b_hh,
        float* __restrict__ gi, float* __restrict__ gh) {
    int n0 = blockIdx.x * 128, m0 = blockIdx.y * 128;
    const bf16* A  = blockIdx.z ? btb : mb;
    const bf16* Bm = blockIdx.z ? Whh_b : Wih_b;
    const float* bias = blockIdx.z ? b_hh : b_ih;
    float* C = blockIdx.z ? gh : gi;
    gemm_core2<128, 128, false>(
        A + (size_t)m0 * D_, D_, Bm + (size_t)n0 * 512, 512, bias + n0,
        C + (size_t)m0 * TD_ + n0, TD_, 128);
}

// ---------------- attention + LN(m_t) ----------------
__global__ void __launch_bounds__(256) k_attn(
        const float* __restrict__ q, const bf16* __restrict__ kv,
        const int* __restrict__ stc, const float* __restrict__ lng_g,
        const float* __restrict__ lng_b, float* __restrict__ mf,
        bf16* __restrict__ mb) {
    int b = blockIdx.x;
    int t = threadIdx.x, w = t >> 6, lane = t & 63;
    int slen = stc[b];
    const float* qp = q + (size_t)b * D_ + lane * 8;
    float4 qa = *(const float4*)qp, qb4 = *(const float4*)(qp + 4);
    float qv[8] = {qa.x, qa.y, qa.z, qa.w, qb4.x, qb4.y, qb4.z, qb4.w};
    float acc[8] = {0,0,0,0,0,0,0,0};
    const bf16* kvb = kv + (size_t)b * S_ * 1024 + lane * 8;
    for (int s = w; s < slen; s += 4) {
        union { uint4 u; bf16 h[8]; } kl, vl;
        kl.u = *(const uint4*)(kvb + (size_t)s * 1024);
        float part = 0.f;
#pragma unroll
        for (int j = 0; j < 8; ++j) part += qv[j] * __bfloat162float(kl.h[j]);
        part += __shfl_xor(part, 1);
        part += __shfl_xor(part, 2);
        part += __shfl_xor(part, 4);   // 8-lane group: full 64-dim head dot
        float p = 1.f / (1.f + __expf(-part * 0.125f));
        vl.u = *(const uint4*)(kvb + (size_t)s * 1024 + 512);
#pragma unroll
        for (int j = 0; j < 8; ++j) acc[j] += p * __bfloat162float(vl.h[j]);
    }
    __shared__ float macc[4][D_];
#pragma unroll
    for (int j = 0; j < 8; ++j) macc[w][lane * 8 + j] = acc[j];
    __syncthreads();
    __shared__ float red[256];
    int d1 = t + 256;
    float x0 = macc[0][t] + macc[1][t] + macc[2][t] + macc[3][t];
    float x1 = macc[0][d1] + macc[1][d1] + macc[2][d1] + macc[3][d1];
    red[t] = x0 + x1; __syncthreads();
    for (int st = 128; st; st >>= 1) {
        if (t < st) red[t] += red[t + st];
        __syncthreads();
    }
    float mean = red[0] * (1.f / 512.f); __syncthreads();
    float c0 = x0 - mean, c1 = x1 - mean;
    red[t] = c0 * c0 + c1 * c1; __syncthreads();
    for (int st = 128; st; st >>= 1) {
        if (t < st) red[t] += red[t + st];
        __syncthreads();
    }
    float rstd = rsqrtf(red[0] * (1.f / 512.f) + 1e-5f);
    float y0 = c0 * rstd * lng_g[t] + lng_b[t];
    float y1 = c1 * rstd * lng_g[d1] + lng_b[d1];
    mf[(size_t)b * D_ + t] = y0;
    mf[(size_t)b * D_ + d1] = y1;
    mb[(size_t)b * D_ + t] = __float2bfloat16(y0);
    mb[(size_t)b * D_ + d1] = __float2bfloat16(y1);
}

// ---------------- GRU elementwise update ----------------
__global__ void __launch_bounds__(256) k_gru(
        const float* __restrict__ gi, const float* __restrict__ gh,
        float* __restrict__ bt, bf16* __restrict__ btb) {
    int i = blockIdx.x * 256 + threadIdx.x;
    int b = i >> 9, d = i & 511;
    const float* gib = gi + (size_t)b * TD_;
    const float* ghb = gh + (size_t)b * TD_;
    float ir = gib[d], iz = gib[512 + d], inn = gib[1024 + d];
    float hr = ghb[d], hz = ghb[512 + d], hn = ghb[1024 + d];
    float r = 1.f / (1.f + expf(-(ir + hr)));
    float z = 1.f / (1.f + expf(-(iz + hz)));
    float n = tanhf(inn + r * hn);
    float bo = bt[i];
    float bn = (1.f - z) * n + z * bo;
    bt[i] = bn;
    btb[i] = __float2bfloat16(bn);
}

// ---------------- launch ----------------
extern "C" void kernel_launch(void* const* d_in, const int* in_sizes, int n_in,
                              void* d_out, int out_size, void* d_ws, size_t ws_size,
                              hipStream_t stream) {
    const float* emb   = (const float*)d_in[0];
    const int*   stc   = (const int*)d_in[1];
    const int*   offs  = (const int*)d_in[2];
    const int*   sep   = (const int*)d_in[3];
    const float* W1    = (const float*)d_in[4];
    const float* W2    = (const float*)d_in[5];
    const float* ln_g  = (const float*)d_in[6];
    const float* ln_b  = (const float*)d_in[7];
    const float* lng_g = (const float*)d_in[8];
    const float* lng_b = (const float*)d_in[9];
    const float* Wq    = (const float*)d_in[10];
    const float* bq    = (const float*)d_in[11];
    const float* Wk    = (const float*)d_in[12];
    const float* bk    = (const float*)d_in[13];
    const float* Wv    = (const float*)d_in[14];
    const float* bv    = (const float*)d_in[15];
    const float* W_ih  = (const float*)d_in[16];
    const float* W_hh  = (const float*)d_in[17];
    const float* b_ih  = (const float*)d_in[18];
    const float* b_hh  = (const float*)d_in[19];
    const float* seg_e = (const float*)d_in[20];
    const float* pe    = (const float*)d_in[21];

    char* base = (char*)d_ws;
    size_t off = 0;
    auto alloc = [&](size_t bytes) -> void* {
        off = (off + 255) & ~(size_t)255;
        void* r = base + off;
        off += bytes;
        return r;
    };
    bf16* kv   = (bf16*)alloc(((size_t)B_ * S_ + 64) * 1024 * 2);   // fused K|V
    float* hblk = (float*)alloc((size_t)B_ * LBLK * D_ * 4);
    float* a_s  = (float*)alloc((size_t)B_ * 4 * 4);
    float* scr  = (float*)alloc((size_t)B_ * 4 * 4);
    int*   se   = (int*)alloc((size_t)B_ * 2 * 4);
    float* bt   = (float*)alloc((size_t)B_ * D_ * 4);
    bf16*  btb  = (bf16*)alloc((size_t)B_ * D_ * 2);
    float* qb   = (float*)alloc((size_t)B_ * D_ * 4);
    float* mf   = (float*)alloc((size_t)B_ * D_ * 4);
    bf16*  mb   = (bf16*)alloc((size_t)B_ * D_ * 2);
    float* gi   = (float*)alloc((size_t)B_ * TD_ * 4);
    float* gh   = (float*)alloc((size_t)B_ * TD_ * 4);
    bf16* WqT   = (bf16*)alloc((size_t)D_ * D_ * 2);
    bf16* WkvT  = (bf16*)alloc((size_t)1024 * 512 * 2);
    float* bkv  = (float*)alloc((size_t)1024 * 4);
    bf16* Wih_b = (bf16*)alloc((size_t)TD_ * D_ * 2);
    bf16* Whh_b = (bf16*)alloc((size_t)TD_ * D_ * 2);

    // choose H staging chunk size by remaining workspace
    auto hbytes = [](int ch) { return ((size_t)ch * S_ + 64) * D_ * 2; };
    int CH = 512;
    {
        size_t used = (off + 255) & ~(size_t)255;
        size_t remain = (ws_size > used) ? (ws_size - used) : 0;
        if (hbytes(512) + 256 > remain) CH = 64;
        if (CH == 64 && hbytes(64) + 256 > remain) CH = 16;
    }
    bf16* Hc = (bf16*)alloc(hbytes(CH));

    // weight prep (single launch)
    {
        int total = 512*512 + 1024*512 + 2*TD_*D_ + 1024;
        k_prep<<<(total + 255) / 256, 256, 0, stream>>>(
            Wq, Wk, Wv, bk, bv, W_ih, W_hh, WqT, WkvT, bkv, Wih_b, Whh_b);
    }

    // block-score path -> b_t init
    k_blockscore<<<B_, 256, 0, stream>>>(emb, W1, W2, stc, offs, sep, hblk, a_s, se);
    k_score<<<1, 512, 0, stream>>>(a_s, se, scr);
    k_b0<<<B_, 64, 0, stream>>>(hblk, scr, pe, ln_g, ln_b, bt, btb);

    // H -> fused K/V projection (chunked over batches)
    for (int c = 0; c < B_; c += CH) {
        int rows = CH * S_;
        k_H<<<(rows + 3) / 4, 256, 0, stream>>>(emb, pe, seg_e, ln_g, ln_b,
                                                stc, offs, Hc, c, rows);
        k_gemm_kv2<<<dim3(8, 2, CH), 256, 0, stream>>>(Hc, WkvT, bkv, kv, stc, c);
    }

    // 3 GRU iterations
    for (int it = 0; it < NITER; ++it) {
        k_gemm_q<<<dim3(4, 4), 256, 0, stream>>>(btb, WqT, bq, qb);
        k_attn<<<B_, 256, 0, stream>>>(qb, kv, stc, lng_g, lng_b, mf, mb);
        k_gemm_gates<<<dim3(12, 4, 2), 256, 0, stream>>>(mb, btb, Wih_b, Whh_b,
                                                         b_ih, b_hh, gi, gh);
        k_gru<<<(B_ * D_) / 256, 256, 0, stream>>>(gi, gh, bt, btb);
    }
    hipMemcpyAsync(d_out, bt, (size_t)out_size * sizeof(float),
                   hipMemcpyDeviceToDevice, stream);
}